// Round 3
// baseline (163.823 us; speedup 1.0000x reference)
//
#include <hip/hip_runtime.h>

#define D_ 64
#define L_ 50
#define B_ 4096
#define T_ 100
#define RS 72    // bf16 eb row stride (144 B, 16B-aligned for b128)

typedef __attribute__((ext_vector_type(8))) short  short8;   // 8 bf16 = 4 VGPRs
typedef __attribute__((ext_vector_type(4))) float  float4v;  // MFMA acc
typedef __attribute__((ext_vector_type(4))) unsigned short ushort4v;

__device__ __forceinline__ float sigmoidf_(float x) {
    return 1.0f / (1.0f + __expf(-x));
}
__device__ __forceinline__ unsigned short f2bf(float x) {   // RNE f32->bf16
    unsigned u = __builtin_bit_cast(unsigned, x);
    return (unsigned short)((u + 0x7fffu + ((u >> 16) & 1u)) >> 16);
}
__device__ __forceinline__ float bf2f(unsigned short s) {
    return __builtin_bit_cast(float, (unsigned)s << 16);
}

// Prelude (runs once per launch, ~16 KB): wbT[c*64+k] = bf16(W[k][c])
__global__ __launch_bounds__(256) void hgn_transpose_w(
    const float* __restrict__ fg_item_W, unsigned short* __restrict__ wbT)
{
    const int i = blockIdx.x * 256 + threadIdx.x;   // i over 4096
    const int k = i >> 6, c = i & 63;
    wbT[c * 64 + k] = f2bf(fg_item_W[i]);           // coalesced read, scattered write
}

// Main: one block (4 waves) per batch b. VGPR must stay <= 64 (residency
// quantum halves past 64: measured round-1). Post-MFMA reductions are done
// in-register via shfl butterflies: no gi LDS buffer, no single-wave serial
// phases, 4 barriers instead of 5.
__global__ __launch_bounds__(256) void hgn_fused_kernel(
    const int* __restrict__ item_seq,          // [B,L]
    const int* __restrict__ user_ids,          // [B]
    const int* __restrict__ items_to_predict,  // [B,T]
    const float* __restrict__ user_emb_table,  // [U,D]
    const float* __restrict__ item_emb_table,  // [I,D]
    const unsigned short* __restrict__ wbT,    // [64,64] bf16 W^T (precomputed)
    const float* __restrict__ fg_item_b,       // [D]
    const float* __restrict__ fg_user_W,       // [D,D]
    const float* __restrict__ fg_user_b,       // [D]
    const float* __restrict__ ig_item,         // [D]
    const float* __restrict__ ig_user,         // [D,L]
    const float* __restrict__ W2,              // [I,D]
    const float* __restrict__ b2,              // [I]
    float* __restrict__ out)                   // [B,T]
{
    __shared__ unsigned short eb_sh[64 * RS];          // 9216 B: E rows bf16
    __shared__ __align__(16) float u_sh[D_];
    __shared__ __align__(16) float v_sh[D_];
    __shared__ float gb_sh[D_];
    __shared__ float usl_sh[D_];                       // u . ig_user[:,l]  (l<50 valid)
    __shared__ __align__(16) float red_sh[4][128];     // per-wave {union,esum} pairs
    __shared__ float ss_sh[4];
    __shared__ int   idx_sh[D_];                       // 50 used

    const int t    = threadIdx.x;
    const int lane = t & 63;
    const int wave = t >> 6;
    const int b    = blockIdx.x;

    if (t < L_) idx_sh[t] = item_seq[b * L_ + t];
    if (t >= 64 && t < 128) {
        const int uid = user_ids[b];
        u_sh[t - 64] = user_emb_table[(size_t)uid * D_ + (t - 64)];
    }
    // Hoist phase-D index + b2 gathers to the top: breaks the dependent
    // (index load -> b2/W2 gather) chain at the end of the kernel. +2 VGPR.
    int   idxt  = 0;
    float b2pre = 0.f;
    if (t < 2 * T_) {
        idxt  = items_to_predict[b * T_ + (t >> 1)];
        b2pre = b2[idxt];
    }
    __syncthreads();   // idx_sh / u_sh ready

    if (wave == 3) {
        // gbias[d] = fg_item_b + fg_user_b + u @ fg_user_W (coalesced, L1-hot)
        float g0 = fg_item_b[lane], g1 = fg_user_b[lane], g2 = 0.f, g3 = 0.f;
#pragma unroll
        for (int k = 0; k < D_; k += 4) {
            g0 = fmaf(u_sh[k + 0], fg_user_W[(k + 0) * D_ + lane], g0);
            g1 = fmaf(u_sh[k + 1], fg_user_W[(k + 1) * D_ + lane], g1);
            g2 = fmaf(u_sh[k + 2], fg_user_W[(k + 2) * D_ + lane], g2);
            g3 = fmaf(u_sh[k + 3], fg_user_W[(k + 3) * D_ + lane], g3);
        }
        gb_sh[lane] = (g0 + g1) + (g2 + g3);
        // usl[l] = u . ig_user[:,l]  (ig_user is [D,L] f32, 12.8 KB, L2-hot)
        if (lane < L_) {
            float us0 = 0.f, us1 = 0.f;
#pragma unroll
            for (int d = 0; d < D_; d += 2) {
                us0 = fmaf(u_sh[d + 0], ig_user[(d + 0) * L_ + lane], us0);
                us1 = fmaf(u_sh[d + 1], ig_user[(d + 1) * L_ + lane], us1);
            }
            usl_sh[lane] = us0 + us1;
        }
    } else {
        // waves 0-2 (192 threads): stage E as bf16. Explicit 4+1 batching:
        // all loads issued before any convert/write (4-5 in flight per lane).
        const int base = wave * 64 + lane;             // 0..191
        const int c0 = base, c1 = base + 192, c2 = base + 384, c3 = base + 576,
                  c4 = base + 768;
        const bool tail = (base < 32);                 // 800 = 4*192 + 32
        float4 r0 = ((const float4*)(item_emb_table + (size_t)idx_sh[c0 >> 4] * D_))[c0 & 15];
        float4 r1 = ((const float4*)(item_emb_table + (size_t)idx_sh[c1 >> 4] * D_))[c1 & 15];
        float4 r2 = ((const float4*)(item_emb_table + (size_t)idx_sh[c2 >> 4] * D_))[c2 & 15];
        float4 r3 = ((const float4*)(item_emb_table + (size_t)idx_sh[c3 >> 4] * D_))[c3 & 15];
        float4 r4 = {0.f, 0.f, 0.f, 0.f};
        if (tail)
            r4 = ((const float4*)(item_emb_table + (size_t)idx_sh[c4 >> 4] * D_))[c4 & 15];
        {
            ushort4v o0 = { f2bf(r0.x), f2bf(r0.y), f2bf(r0.z), f2bf(r0.w) };
            *(ushort4v*)&eb_sh[(c0 >> 4) * RS + (c0 & 15) * 4] = o0;
            ushort4v o1 = { f2bf(r1.x), f2bf(r1.y), f2bf(r1.z), f2bf(r1.w) };
            *(ushort4v*)&eb_sh[(c1 >> 4) * RS + (c1 & 15) * 4] = o1;
            ushort4v o2 = { f2bf(r2.x), f2bf(r2.y), f2bf(r2.z), f2bf(r2.w) };
            *(ushort4v*)&eb_sh[(c2 >> 4) * RS + (c2 & 15) * 4] = o2;
            ushort4v o3 = { f2bf(r3.x), f2bf(r3.y), f2bf(r3.z), f2bf(r3.w) };
            *(ushort4v*)&eb_sh[(c3 >> 4) * RS + (c3 & 15) * 4] = o3;
            if (tail) {
                ushort4v o4 = { f2bf(r4.x), f2bf(r4.y), f2bf(r4.z), f2bf(r4.w) };
                *(ushort4v*)&eb_sh[(c4 >> 4) * RS + (c4 & 15) * 4] = o4;
            }
        }
    }
    __syncthreads();   // eb / gb / usl ready

    // ---- MFMA gate matmul + fully in-register score/union/esum reductions.
    // Wave w owns P rows [16w,16w+16). Lane (q,m): D rows l=16w+4q+r, cols 16n+m.
    {
        const int m = lane & 15, q = lane >> 4;
        const int arow = 16 * wave + m;
        const short8 a0 = *(const short8*)&eb_sh[arow * RS + q * 8];       // k 0..31
        const short8 a1 = *(const short8*)&eb_sh[arow * RS + 32 + q * 8];  // k 32..63

        float gi[4][4];                  // gated item values (n, r)
        float ep[4];                     // esum partial per n (sum over r)
        float sp[4] = {0.f, 0.f, 0.f, 0.f};   // score partial per r (sum over own cols)
#pragma unroll
        for (int n = 0; n < 4; ++n) {
            const int col = 16 * n + m;
            const short8 b0 = *(const short8*)&wbT[col * 64 + q * 8];      // L1-hot
            const short8 b1 = *(const short8*)&wbT[col * 64 + 32 + q * 8];
            float4v acc = {0.f, 0.f, 0.f, 0.f};
            acc = __builtin_amdgcn_mfma_f32_16x16x32_bf16(a0, b0, acc, 0, 0, 0);
            acc = __builtin_amdgcn_mfma_f32_16x16x32_bf16(a1, b1, acc, 0, 0, 0);
            const float gbc = gb_sh[col];
            const float igc = ig_item[col];                                // L1-hot
            float epn = 0.f;
#pragma unroll
            for (int r = 0; r < 4; ++r) {
                const int l = 16 * wave + q * 4 + r;
                float gv = 0.f;
                if (l < L_) {            // mask garbage rows (wave 3, l>=50)
                    const float e = bf2f(eb_sh[l * RS + col]);
                    gv  = e * sigmoidf_(acc[r] + gbc);
                    epn += e;
                    sp[r] = fmaf(gv, igc, sp[r]);
                }
                gi[n][r] = gv;
            }
            ep[n] = epn;
        }

        // m-butterfly: sum sp[r] over the 16 m-lanes (full-d score for row l)
#pragma unroll
        for (int r = 0; r < 4; ++r) {
            float v = sp[r];
            v += __shfl_xor(v, 1);  v += __shfl_xor(v, 2);
            v += __shfl_xor(v, 4);  v += __shfl_xor(v, 8);
            sp[r] = v;
        }
        // instance score s[l] in-lane; masked 0 for l>=50
        float s[4];
        float ssr = 0.f;
#pragma unroll
        for (int r = 0; r < 4; ++r) {
            const int l = 16 * wave + q * 4 + r;
            const float sv = (l < L_) ? sigmoidf_(sp[r] + usl_sh[l]) : 0.f;
            s[r] = sv;
            ssr += sv;
        }
        // q-butterfly: wave ssum
        ssr += __shfl_xor(ssr, 16);  ssr += __shfl_xor(ssr, 32);
        if (lane == 0) ss_sh[wave] = ssr;

        // union/esum partials per n; q-butterfly to per-wave totals
        float unA[4], enA[4];
#pragma unroll
        for (int n = 0; n < 4; ++n) {
            float un = fmaf(gi[n][0], s[0], fmaf(gi[n][1], s[1],
                        fmaf(gi[n][2], s[2], gi[n][3] * s[3])));
            un += __shfl_xor(un, 16);  un += __shfl_xor(un, 32);
            float en = ep[n];
            en += __shfl_xor(en, 16);  en += __shfl_xor(en, 32);
            unA[n] = un;  enA[n] = en;
        }
        // lane stores the pair for col 16q+m -> one contiguous ds_write_b64/wave
        const float unq = (q == 0) ? unA[0] : (q == 1) ? unA[1] : (q == 2) ? unA[2] : unA[3];
        const float enq = (q == 0) ? enA[0] : (q == 1) ? enA[1] : (q == 2) ? enA[2] : enA[3];
        float2 pr;  pr.x = unq;  pr.y = enq;
        *(float2*)&red_sh[wave][(16 * q + m) * 2] = pr;
    }
    __syncthreads();   // red / ss ready

    // ---- v finalize (one wave, ~10 LDS ops)
    if (wave == 0) {
        float un = 0.f, en = 0.f;
#pragma unroll
        for (int w = 0; w < 4; ++w) {
            const float2 pr = *(const float2*)&red_sh[w][lane * 2];
            un += pr.x;  en += pr.y;
        }
        const float ss = (ss_sh[0] + ss_sh[1]) + (ss_sh[2] + ss_sh[3]);
        v_sh[lane] = u_sh[lane] + un / ss + en;
    }
    __syncthreads();   // v_sh ready

    // ---- Phase D: 2 threads per (b,t), half-row dots, combine via shfl
    if (t < 2 * T_) {
        const int half = t & 1;
        const float* wrow  = W2 + (size_t)idxt * D_ + half * 32;
        const float* vhalf = v_sh + half * 32;
        float r0 = 0.f, r1 = 0.f, r2 = 0.f, r3 = 0.f;
#pragma unroll
        for (int kk = 0; kk < 8; ++kk) {
            const float4 w4 = ((const float4*)wrow)[kk];
            const float4 v4 = ((const float4*)vhalf)[kk];
            r0 = fmaf(v4.x, w4.x, r0);
            r1 = fmaf(v4.y, w4.y, r1);
            r2 = fmaf(v4.z, w4.z, r2);
            r3 = fmaf(v4.w, w4.w, r3);
        }
        float r = (r0 + r1) + (r2 + r3);
        r += __shfl_xor(r, 1, 64);
        if (half == 0) out[b * T_ + (t >> 1)] = r + b2pre;
    }
}

extern "C" void kernel_launch(void* const* d_in, const int* in_sizes, int n_in,
                              void* d_out, int out_size, void* d_ws, size_t ws_size,
                              hipStream_t stream) {
    const int*   item_seq   = (const int*)d_in[0];
    const int*   user_ids   = (const int*)d_in[1];
    const int*   items_pred = (const int*)d_in[2];
    const float* uet        = (const float*)d_in[3];
    const float* iet        = (const float*)d_in[4];
    const float* fgiW       = (const float*)d_in[5];
    const float* fgib       = (const float*)d_in[6];
    const float* fguW       = (const float*)d_in[7];
    const float* fgub       = (const float*)d_in[8];
    const float* igi        = (const float*)d_in[9];
    const float* igu        = (const float*)d_in[10];
    const float* W2         = (const float*)d_in[11];
    const float* b2t        = (const float*)d_in[12];

    unsigned short* wbT = (unsigned short*)d_ws;   // 8 KB bf16 W^T

    hgn_transpose_w<<<16, 256, 0, stream>>>(fgiW, wbT);
    hgn_fused_kernel<<<B_, 256, 0, stream>>>(
        item_seq, user_ids, items_pred, uet, iet,
        wbT, fgib, fguW, fgub, igi, igu, W2, b2t, (float*)d_out);
}